// Round 16
// baseline (944.779 us; speedup 1.0000x reference)
//
#include <hip/hip_runtime.h>
#include <hip/hip_bf16.h>

#define DIM   1536
#define HEADS 12
#define HD    128
#define LSEQ  2048
#define NB    2
#define NTOK  (NB*LSEQ)   // 4096

using f32x4  = __attribute__((ext_vector_type(4))) float;
using f32x16 = __attribute__((ext_vector_type(16))) float;
using s16x8  = __attribute__((ext_vector_type(8))) short;
using u16x4  = __attribute__((ext_vector_type(4))) unsigned short;

__device__ __forceinline__ unsigned short f2bf(float f) {
  unsigned int u = __builtin_bit_cast(unsigned int, f);
  u += 0x7fffu + ((u >> 16) & 1u);   // RNE
  return (unsigned short)(u >> 16);
}
__device__ __forceinline__ float bf2f(unsigned short u) {
  return __builtin_bit_cast(float, (unsigned int)u << 16);
}
// HW packed f32x2 -> bf16x2 (lo=a, hi=b), RNE
__device__ __forceinline__ unsigned pk2(float a, float b) {
  unsigned r;
  asm("v_cvt_pk_bf16_f32 %0, %1, %2" : "=v"(r) : "v"(a), "v"(b));
  return r;
}
__device__ __forceinline__ unsigned long long pack4bf(float a, float b, float c, float d) {
  return (unsigned long long)f2bf(a) | ((unsigned long long)f2bf(b) << 16) |
         ((unsigned long long)f2bf(c) << 32) | ((unsigned long long)f2bf(d) << 48);
}
// swaps x.lanes[32:63] <-> y.lanes[0:31]
__device__ __forceinline__ void plswap(unsigned &x, unsigned &y) {
  asm volatile("v_permlane32_swap_b32 %0, %1" : "+v"(x), "+v"(y));
}
__device__ __forceinline__ void gload_lds16(const void* g, void* l) {
  __builtin_amdgcn_global_load_lds(
      (__attribute__((address_space(1))) void*)const_cast<void*>(g),
      (__attribute__((address_space(3))) void*)l,
      16, 0, 0);
}

// ---- prep: wtrans (blocks 0..2303) || cvt_x (blocks 2304..3327) ----
__global__ __launch_bounds__(256) void prep(
    const float* __restrict__ x, unsigned short* __restrict__ xb,
    const float* __restrict__ W0, const float* __restrict__ W1,
    const float* __restrict__ W2, const float* __restrict__ W3,
    unsigned short* __restrict__ Wt) {
  __shared__ unsigned short t[64][68];
  const int bid = blockIdx.x;
  const int tid = threadIdx.x;
  if (bid < 2304) {
    const int z = bid / 576, rem = bid % 576;
    const float* W = z == 0 ? W0 : z == 1 ? W1 : z == 2 ? W2 : W3;
    unsigned short* out = Wt + (size_t)z * DIM * DIM;
    const int n0 = (rem % 24) * 64, k0 = (rem / 24) * 64;
#pragma unroll
    for (int i = 0; i < 16; i++) {
      int idx = tid + i * 256;
      int r = idx >> 6, c = idx & 63;
      t[r][c] = f2bf(W[(size_t)(k0 + r) * DIM + n0 + c]);
    }
    __syncthreads();
#pragma unroll
    for (int i = 0; i < 16; i++) {
      int idx = tid + i * 256;
      int r = idx >> 6, c = idx & 63;
      out[(size_t)(n0 + r) * DIM + k0 + c] = t[c][r];
    }
  } else {
    int i = ((bid - 2304) * 256 + tid) * 4;
    int stride = 1024 * 256 * 4;
    for (; i < NTOK * DIM; i += stride) {
      f32x4 v = *(const f32x4*)(x + i);
      u16x4 o;
      o[0] = f2bf(v[0]); o[1] = f2bf(v[1]); o[2] = f2bf(v[2]); o[3] = f2bf(v[3]);
      *(u16x4*)(xb + i) = o;
    }
  }
}

// ---- GEMM 256x256 tile, BK=32, 8 waves, flash-style counted-vmcnt dbuf ----
// 64KB LDS -> 2 blocks/CU, 288 blocks all-resident (no tail).
__global__ __launch_bounds__(512, 4) void gemm256b(
    const unsigned short* __restrict__ A, const unsigned short* __restrict__ Bt,
    void* __restrict__ Cv,
    const float* __restrict__ b0, const float* __restrict__ b1, const float* __restrict__ b2,
    int M, int N, int K, int biasMode, int outBf16) {
  __shared__ __align__(16) unsigned short As[2][256 * 32];  // 16KB each
  __shared__ __align__(16) unsigned short Bs[2][256 * 32];
  const int tid = threadIdx.x;
  const int lane = tid & 63;
  const int l15 = lane & 15, g4 = lane >> 4;
  const int wid = tid >> 6, wr = wid >> 2, wc = wid & 3;   // 2M x 4N waves
  // XCD-aware bijective swizzle (nwg % 8 == 0)
  const int nwg = gridDim.x * gridDim.y;
  const int bidf = blockIdx.y * gridDim.x + blockIdx.x;
  const int cpx = nwg >> 3;
  const int sw = (bidf & 7) * cpx + (bidf >> 3);
  const int m0 = (sw / gridDim.x) * 256, n0 = (sw % gridDim.x) * 256;

  f32x4 acc[8][4];
#pragma unroll
  for (int i = 0; i < 8; i++)
#pragma unroll
    for (int j = 0; j < 4; j++) acc[i][j] = (f32x4){0.f, 0.f, 0.f, 0.f};

  // stage one 256x32 operand tile: 1024 chunks / 512 thr = 2 each; mask row&3
#define SG_A(T, BUF)                                                                   \
  _Pragma("unroll") for (int i = 0; i < 2; i++) {                                      \
    int cc = tid + i * 512, row = cc >> 2, ch = cc & 3, gs = ch ^ (row & 3);           \
    gload_lds16(A + (size_t)(m0 + row) * K + (T) * 32 + gs * 8, &As[BUF][0] + cc * 8); \
  }
#define SG_B(T, BUF)                                                                   \
  _Pragma("unroll") for (int i = 0; i < 2; i++) {                                      \
    int cc = tid + i * 512, row = cc >> 2, ch = cc & 3, gs = ch ^ (row & 3);           \
    gload_lds16(Bt + (size_t)(n0 + row) * K + (T) * 32 + gs * 8, &Bs[BUF][0] + cc * 8); \
  }
#define RD(BASE, R) \
  (*(const s16x8*)((BASE) + (R) * 64 + ((g4 * 16) ^ (((R) & 3) << 4))))

  const int NT = K >> 5;   // 48 for K=1536
  // prologue: T0->buf0, T1->buf1 (8 loads/thread outstanding)
  SG_A(0, 0); SG_B(0, 0);
  SG_A(1, 1); SG_B(1, 1);

  for (int T = 0; T < NT; T++) {
    const int cur = T & 1;
    // pair(T) = oldest 4 landed; pair(T+1)'s 4 stay in flight across barrier
    asm volatile("s_waitcnt vmcnt(4)" ::: "memory");
    __builtin_amdgcn_s_barrier();
    __builtin_amdgcn_sched_barrier(0);
    const char* ab = (const char*)&As[cur][0];
    const char* bb = (const char*)&Bs[cur][0];
    s16x8 af[8], bf[4];
#pragma unroll
    for (int m = 0; m < 8; m++) { int lr = wr * 128 + m * 16 + l15; af[m] = RD(ab, lr); }
#pragma unroll
    for (int n = 0; n < 4; n++) { int rb = wc * 64 + n * 16 + l15; bf[n] = RD(bb, rb); }
    __builtin_amdgcn_s_setprio(1);
#pragma unroll
    for (int m = 0; m < 8; m++)
#pragma unroll
      for (int n = 0; n < 4; n++)
        acc[m][n] = __builtin_amdgcn_mfma_f32_16x16x32_bf16(af[m], bf[n], acc[m][n], 0, 0, 0);
    __builtin_amdgcn_s_setprio(0);
    // all waves done reading buf[cur] -> restage it with pair(T+2)
    __builtin_amdgcn_s_barrier();
    __builtin_amdgcn_sched_barrier(0);
    {
      int Tn = (T + 2 < NT) ? T + 2 : T;   // dummy keeps vmcnt uniform
      SG_A(Tn, cur); SG_B(Tn, cur);
    }
  }
  asm volatile("s_waitcnt vmcnt(0)" ::: "memory");
#undef SG_A
#undef SG_B
#undef RD
  // epilogue
#pragma unroll
  for (int m = 0; m < 8; m++)
#pragma unroll
    for (int n = 0; n < 4; n++)
#pragma unroll
      for (int r = 0; r < 4; r++) {
        int grow = m0 + wr * 128 + m * 16 + g4 * 4 + r;
        int gcol = n0 + wc * 64 + n * 16 + l15;
        float bias = (biasMode == 1)
                         ? b0[gcol]
                         : (gcol < 1536 ? b0[gcol]
                                        : (gcol < 3072 ? b1[gcol - 1536] : b2[gcol - 3072]));
        float val = acc[m][n][r] + bias;
        if (outBf16) ((unsigned short*)Cv)[(size_t)grow * N + gcol] = f2bf(val);
        else         ((float*)Cv)[(size_t)grow * N + gcol] = val;
      }
}

// ---------------- GEMM: 128x128 tile (m97-structure) — used for gemm2 ----------------
__global__ __launch_bounds__(256) void gemm_bt(
    const unsigned short* __restrict__ A, const unsigned short* __restrict__ Bt,
    void* __restrict__ Cv,
    const float* __restrict__ b0, const float* __restrict__ b1, const float* __restrict__ b2,
    int M, int N, int K, int biasMode, int outBf16) {
  __shared__ __align__(16) unsigned short As[128 * 64];
  __shared__ __align__(16) unsigned short Bs[128 * 64];
  const int tid = threadIdx.x;
  const int lane = tid & 63, w = tid >> 6;
  const int wr = w >> 1, wc = w & 1;
  const int l15 = lane & 15, g4 = lane >> 4;
  const int nwg = gridDim.x * gridDim.y;
  const int bidf = blockIdx.y * gridDim.x + blockIdx.x;
  const int cpx = nwg >> 3;
  const int sw = (bidf & 7) * cpx + (bidf >> 3);
  const int m0 = (sw / gridDim.x) * 128, n0 = (sw % gridDim.x) * 128;

  f32x4 acc[4][4];
#pragma unroll
  for (int i = 0; i < 4; i++)
#pragma unroll
    for (int j = 0; j < 4; j++) acc[i][j] = (f32x4){0.f, 0.f, 0.f, 0.f};

  for (int kt = 0; kt < K; kt += 64) {
    __syncthreads();
#pragma unroll
    for (int i = 0; i < 4; i++) {
      int c = tid + i * 256;
      int row = c >> 3, g = c & 7;
      int gs = g ^ (row & 7);
      gload_lds16(A + (size_t)(m0 + row) * K + kt + gs * 8, As + c * 8);
    }
#pragma unroll
    for (int i = 0; i < 4; i++) {
      int c = tid + i * 256;
      int row = c >> 3, g = c & 7;
      int gs = g ^ (row & 7);
      gload_lds16(Bt + (size_t)(n0 + row) * K + kt + gs * 8, Bs + c * 8);
    }
    __syncthreads();
#pragma unroll
    for (int kk = 0; kk < 2; kk++) {
      s16x8 af[4], bfr[4];
#pragma unroll
      for (int m = 0; m < 4; m++) {
        int row = wr * 64 + m * 16 + l15;
        int off = row * 128 + ((kk * 64 + g4 * 16) ^ ((row & 7) << 4));
        af[m] = *(const s16x8*)((const char*)As + off);
      }
#pragma unroll
      for (int n = 0; n < 4; n++) {
        int row = wc * 64 + n * 16 + l15;
        int off = row * 128 + ((kk * 64 + g4 * 16) ^ ((row & 7) << 4));
        bfr[n] = *(const s16x8*)((const char*)Bs + off);
      }
#pragma unroll
      for (int m = 0; m < 4; m++)
#pragma unroll
        for (int n = 0; n < 4; n++)
          acc[m][n] = __builtin_amdgcn_mfma_f32_16x16x32_bf16(af[m], bfr[n], acc[m][n], 0, 0, 0);
    }
  }
#pragma unroll
  for (int m = 0; m < 4; m++)
#pragma unroll
    for (int n = 0; n < 4; n++)
#pragma unroll
      for (int r = 0; r < 4; r++) {
        int grow = m0 + wr * 64 + m * 16 + g4 * 4 + r;
        int gcol = n0 + wc * 64 + n * 16 + l15;
        float bias = (biasMode == 1)
                         ? b0[gcol]
                         : (gcol < 1536 ? b0[gcol]
                                        : (gcol < 3072 ? b1[gcol - 1536] : b2[gcol - 3072]));
        float val = acc[m][n][r] + bias;
        if (outBf16) ((unsigned short*)Cv)[(size_t)grow * N + gcol] = f2bf(val);
        else         ((float*)Cv)[(size_t)grow * N + gcol] = val;
      }
}

// ---- rmsv: rmsrope (blocks 0..4095) || vtrans (blocks 4096..4863) ----
__global__ __launch_bounds__(256) void rmsv(
    const unsigned short* __restrict__ qkvb,   // [4096][4608] bf16
    const float* __restrict__ gq, const float* __restrict__ gk,
    const int* __restrict__ grid_sizes,
    const float* __restrict__ fcos, const float* __restrict__ fsin,
    unsigned short* __restrict__ qb, unsigned short* __restrict__ kb,
    unsigned short* __restrict__ vt) {
  __shared__ float qrow[1536], krow[1536];
  __shared__ float red[8];
  __shared__ unsigned short tile[64][130];
  const int tid = threadIdx.x;
  if (blockIdx.x < 4096) {
    const int t = blockIdx.x;
    const int b = t >> 11, l = t & 2047;
    const unsigned short* rq = qkvb + (size_t)t * 4608;
    const unsigned short* rk = rq + 1536;
    float sq = 0.f, sk = 0.f;
    if (tid < 192) {
      s16x8 vq = *(const s16x8*)(rq + tid * 8);
      s16x8 vk = *(const s16x8*)(rk + tid * 8);
#pragma unroll
      for (int j = 0; j < 8; j++) {
        float a = bf2f((unsigned short)vq[j]); qrow[tid * 8 + j] = a; sq += a * a;
        float c = bf2f((unsigned short)vk[j]); krow[tid * 8 + j] = c; sk += c * c;
      }
    }
    for (int o = 32; o; o >>= 1) { sq += __shfl_down(sq, o); sk += __shfl_down(sk, o); }
    if ((tid & 63) == 0) { red[tid >> 6] = sq; red[4 + (tid >> 6)] = sk; }
    __syncthreads();
    const float rsq = rsqrtf((red[0] + red[1] + red[2] + red[3]) * (1.f / 1536.f) + 1e-6f);
    const float rsk = rsqrtf((red[4] + red[5] + red[6] + red[7]) * (1.f / 1536.f) + 1e-6f);
    const float QS = 0.08838834764831845f * 1.4426950408889634f;  // 1/sqrt(128)*log2e
    const int fg = grid_sizes[b * 3 + 0], hg = grid_sizes[b * 3 + 1], wg = grid_sizes[b * 3 + 2];
    const int hw = hg * wg;
    const bool valid = l < fg * hw;
    const int fi = valid ? l / hw : 0;
    const int hi = valid ? (l / wg) % hg : 0;
    const int wi = valid ? l % wg : 0;
    const size_t obase = (((size_t)b * HEADS) * LSEQ + l) * HD;
    for (int i = tid; i < HEADS * 64; i += 256) {
      int hd = i >> 6, j = i & 63;
      float c, s;
      if (valid) {
        int idx = j < 22 ? fi : (j < 43 ? hi : wi);
        c = fcos[idx * 64 + j]; s = fsin[idx * 64 + j];
      } else { c = 1.f; s = 0.f; }
      int col = hd * 128 + 2 * j;
      size_t o = obase + (size_t)hd * LSEQ * HD + 2 * j;
      float xr = qrow[col] * rsq * gq[col];
      float xi = qrow[col + 1] * rsq * gq[col + 1];
      float q0 = (xr * c - xi * s) * QS, q1 = (xr * s + xi * c) * QS;
      *(unsigned int*)(qb + o) = (unsigned int)f2bf(q0) | ((unsigned int)f2bf(q1) << 16);
      xr = krow[col] * rsk * gk[col];
      xi = krow[col + 1] * rsk * gk[col + 1];
      *(unsigned int*)(kb + o) =
          (unsigned int)f2bf(xr * c - xi * s) | ((unsigned int)f2bf(xr * s + xi * c) << 16);
    }
  } else {
    const int r = blockIdx.x - 4096;            // 0..767
    const int lt = r & 31, hb = r >> 5;
    const int h = hb % 12, b = hb / 12;
    const int l0 = lt * 64;
#pragma unroll
    for (int i = 0; i < 4; i++) {
      int idx = tid + i * 256;
      int tk = idx >> 4, dc = (idx & 15) * 8;
      s16x8 v = *(const s16x8*)(qkvb + (size_t)(b * 2048 + l0 + tk) * 4608 + 3072 + h * 128 + dc);
#pragma unroll
      for (int j = 0; j < 8; j++) tile[tk][dc + j] = (unsigned short)v[j];
    }
    __syncthreads();
    const size_t ob = (((size_t)b * HEADS + h) * HD) * LSEQ + l0;
#pragma unroll
    for (int i = 0; i < 4; i++) {
      int idx = tid + i * 256;
      int d = idx >> 3, ck = (idx & 7) * 8;
      s16x8 o;
#pragma unroll
      for (int j = 0; j < 8; j++) o[j] = (short)tile[ck + j][d];
      *(s16x8*)(vt + ob + (size_t)d * LSEQ + ck) = o;
    }
  }
}

// ---- flash partial: 32x32 swapped, 4-wave blocks (128 q), KVBLK=32, split-2 KV ----
__global__ __launch_bounds__(256) void flash(
    const unsigned short* __restrict__ qb, const unsigned short* __restrict__ kb,
    const unsigned short* __restrict__ vt, const int* __restrict__ seq_lens,
    unsigned short* __restrict__ pO, float* __restrict__ pls, float* __restrict__ pm) {
  // 768 blocks; XCD swizzle: 96 consecutive wg per XCD
  const int orig = blockIdx.x + 16 * (blockIdx.y + 12 * blockIdx.z);
  const int wg = (orig & 7) * 96 + (orig >> 3);
  const int qt = wg & 15;
  const int r4 = wg >> 4;              // 0..47
  const int hh = r4 % 12;
  const int z2 = r4 / 12;              // 0..3
  const int b = z2 >> 1, half = z2 & 1;
  const int tid = threadIdx.x, lane = tid & 63, w = tid >> 6;   // w in {0..3}
  const int l31 = lane & 31, hi = lane >> 5;
  __shared__ __align__(16) unsigned short Ks[2][32 * 128];  // [key][d] 8KB each
  __shared__ __align__(16) unsigned short Vs[2][128 * 32];  // [d][key] 8KB each
  const size_t bh = (size_t)b * HEADS + hh;
  const int q0 = qt * 128 + w * 32;

  s16x8 qf[8];
  {
    const unsigned short* qp = qb + (bh * LSEQ + q0 + l31) * HD + hi * 8;
#pragma unroll
    for (int s = 0; s < 8; s++) qf[s] = *(const s16x8*)(qp + s * 16);
  }
  const int ntile = seq_lens[b] >> 5;        // 64 or 48 (even)
  const int htiles = ntile >> 1;             // 32 or 24 (even)
  const int k0t = half * htiles;             // even
  const int kend = k0t + htiles;
  asm volatile("s_waitcnt vmcnt(0)" ::: "memory");  // drain Q; exact counts below

  f32x16 acc[4];
#pragma unroll
  for (int d = 0; d < 4; d++)
#pragma unroll
    for (int r = 0; r < 16; r++) acc[d][r] = 0.f;
  float mrow = -1e30f, ls = 0.f;

#define STAGE_K(T, BUF)                                                                \
  _Pragma("unroll") for (int i = 0; i < 2; i++) {                                      \
    int c = tid + i * 256, row = c >> 4, seg = c & 15, ss = seg ^ (row & 15);          \
    gload_lds16(kb + (bh * LSEQ + (T) * 32 + row) * HD + ss * 8, &Ks[BUF][0] + c * 8); \
  }
#define STAGE_V(T, BUF)                                                                \
  _Pragma("unroll") for (int i = 0; i < 2; i++) {                                      \
    int c = tid + i * 256, row = c >> 2, seg = c & 3, ss = seg ^ ((row >> 1) & 3);     \
    gload_lds16(vt + (bh * HD + row) * LSEQ + (T) * 32 + ss * 8, &Vs[BUF][0] + c * 8); \
  }

  STAGE_K(k0t, 0); STAGE_V(k0t, 0);
  STAGE_K(k0t + 1, 1); STAGE_V(k0t + 1, 1);

  for (int kt = k0t; kt < kend; kt++) {
    const int cur = kt & 1;
    asm volatile("s_waitcnt vmcnt(4)" ::: "memory");
    __builtin_amdgcn_s_barrier();
    __builtin_amdgcn_sched_barrier(0);
    f32x16 st0;
#pragma unroll
    for (int r = 0; r < 16; r++) st0[r] = 0.f;
    const char* ksb = (const char*)&Ks[cur][0];
    __builtin_amdgcn_s_setprio(1);
#pragma unroll
    for (int s = 0; s < 8; s++) {
      int g = 2 * s + hi;
      s16x8 kf = *(const s16x8*)(ksb + l31 * 256 + ((g ^ (l31 & 15)) << 4));
      st0 = __builtin_amdgcn_mfma_f32_32x32x16_bf16(kf, qf[s], st0, 0, 0, 0);
    }
    __builtin_amdgcn_s_setprio(0);
    f32x16 mt;
#pragma unroll
    for (int r = 0; r < 16; r++) mt[r] = st0[r];
#pragma unroll
    for (int off = 8; off; off >>= 1)
#pragma unroll
      for (int r = 0; r < off; r++) mt[r] = fmaxf(mt[r], mt[r + off]);
    float mx = fmaxf(mt[0], __shfl_xor(mt[0], 32));
    const bool grow = mx > mrow + 8.0f;
    const float alpha = grow ? exp2f(mrow - mx) : 1.f;
    if (grow) mrow = mx;
#pragma unroll
    for (int r = 0; r < 16; r++) st0[r] = exp2f(st0[r] - mrow);
    f32x16 sm;
#pragma unroll
    for (int r = 0; r < 16; r++) sm[r] = st0[r];
#pragma unroll
    for (int off = 8; off; off >>= 1)
#pragma unroll
      for (int r = 0; r < off; r++) sm[r] += sm[r + off];
    ls = ls * alpha + (sm[0] + __shfl_xor(sm[0], 32));
    if (__any((int)grow)) {
#pragma unroll
      for (int d = 0; d < 4; d++)
#pragma unroll
        for (int r = 0; r < 16; r++) acc[d][r] *= alpha;
    }
    union U { unsigned u[4]; s16x8 v; } pa0, pa1;
    {
      unsigned c0 = pk2(st0[0], st0[1]),  c1 = pk2(st0[2], st0[3]);
      unsigned c2 = pk2(st0[4], st0[5]),  c3 = pk2(st0[6], st0[7]);
      unsigned c4 = pk2(st0[8], st0[9]),  c5 = pk2(st0[10], st0[11]);
      unsigned c6 = pk2(st0[12], st0[13]), c7 = pk2(st0[14], st0[15]);
      plswap(c0, c2); plswap(c1, c3); plswap(c4, c6); plswap(c5, c7);
      pa0.u[0] = c0; pa0.u[1] = c1; pa0.u[2] = c2; pa0.u[3] = c3;
      pa1.u[0] = c4; pa1.u[1] = c5; pa1.u[2] = c6; pa1.u[3] = c7;
    }
    const char* vsb = (const char*)&Vs[cur][0];
    __builtin_amdgcn_s_setprio(1);
#pragma unroll
    for (int slot = 0; slot < 2; slot++) {
      s16x8 pb = slot == 0 ? pa0.v : pa1.v;
      int g = 2 * slot + hi;
#pragma unroll
      for (int d = 0; d < 4; d++) {
        int row = d * 32 + l31;
        s16x8 vf = *(const s16x8*)(vsb + row * 64 + ((g ^ ((row >> 1) & 3)) << 4));
        acc[d] = __builtin_amdgcn_mfma_f32_32x32x16_bf16(vf, pb, acc[d], 0, 0, 0);
      }
    }
    __builtin_amdgcn_s_setprio(0);
    __builtin_amdgcn_s_barrier();
    __builtin_amdgcn_sched_barrier(0);
    {
      int knext = (kt + 2 < kend) ? kt + 2 : kt;
      STAGE_K(knext, cur); STAGE_V(knext, cur);
    }
  }
  asm volatile("s_waitcnt vmcnt(0)" ::: "memory");
#undef STAGE_K
#undef STAGE_V
  const int p = ((b * 12 + hh) * 16 + qt) * 2 + half;
  const int ql = w * 32 + l31;                 // 0..127
  unsigned short* pop = pO + ((size_t)p * 128 + ql) * 128 + hi * 4;
#pragma unroll
  for (int d = 0; d < 4; d++)
#pragma unroll
    for (int j = 0; j < 4; j++) {
      unsigned long long pk = pack4bf(acc[d][4 * j], acc[d][4 * j + 1],
                                      acc[d][4 * j + 2], acc[d][4 * j + 3]);
      *(unsigned long long*)(pop + d * 32 + 8 * j) = pk;
    }
  if (hi == 0) {
    pls[(size_t)p * 128 + ql] = ls;
    pm[(size_t)p * 128 + ql] = mrow;
  }
}

// ---- merge two KV-half partials -> attn out [token][h*128+d] bf16 ----
__global__ __launch_bounds__(256) void merge(
    const unsigned short* __restrict__ pO, const float* __restrict__ pls,
    const float* __restrict__ pm, unsigned short* __restrict__ ob) {
  const int qt = blockIdx.x, h = blockIdx.y, b = blockIdx.z;
  const int p0 = ((b * 12 + h) * 16 + qt) * 2;
  const int tid = threadIdx.x;
#pragma unroll
  for (int i = tid; i < 2048; i += 256) {
    int q = i >> 4, c = (i & 15) * 8;
    float m0 = pm[(size_t)p0 * 128 + q],  m1 = pm[(size_t)(p0 + 1) * 128 + q];
    float l0 = pls[(size_t)p0 * 128 + q], l1 = pls[(size_t)(p0 + 1) * 128 + q];
    float m = fmaxf(m0, m1);
    float a0 = exp2f(m0 - m), a1 = exp2f(m1 - m);
    float inv = 1.f / (a0 * l0 + a1 * l1);
    a0 *= inv; a1 *= inv;
    s16x8 o0 = *(const s16x8*)(pO + ((size_t)p0 * 128 + q) * 128 + c);
    s16x8 o1 = *(const s16x8*)(pO + ((size_t)(p0 + 1) * 128 + q) * 128 + c);
    s16x8 o;
#pragma unroll
    for (int j = 0; j < 8; j++)
      o[j] = (short)f2bf(bf2f((unsigned short)o0[j]) * a0 + bf2f((unsigned short)o1[j]) * a1);
    *(s16x8*)(ob + ((size_t)(b * LSEQ) + qt * 128 + q) * DIM + h * HD + c) = o;
  }
}

// ---------------- launch ----------------
extern "C" void kernel_launch(void* const* d_in, const int* in_sizes, int n_in,
                              void* d_out, int out_size, void* d_ws, size_t ws_size,
                              hipStream_t stream) {
  const float* x    = (const float*)d_in[0];
  const int*   seq  = (const int*)d_in[1];
  const int*   grids= (const int*)d_in[2];
  const float* fcos = (const float*)d_in[3];
  const float* fsin = (const float*)d_in[4];
  const float* Wq   = (const float*)d_in[5];
  const float* bq   = (const float*)d_in[6];
  const float* Wk   = (const float*)d_in[7];
  const float* bk   = (const float*)d_in[8];
  const float* Wv   = (const float*)d_in[9];
  const float* bv   = (const float*)d_in[10];
  const float* Wo   = (const float*)d_in[11];
  const float* bo   = (const float*)d_in[12];
  const float* gq   = (const float*)d_in[13];
  const float* gk   = (const float*)d_in[14];

  char* ws = (char*)d_ws;
  unsigned short* xb   = (unsigned short*)(ws);                  // 12.58 MB (reused: attn-out)
  unsigned short* Wt   = (unsigned short*)(ws + 12582912);       // 18.87 MB
  unsigned short* qkvb = (unsigned short*)(ws + 31457280);       // 37.75 MB (dead after rmsv)
  unsigned short* qbb  = (unsigned short*)(ws + 69206016);       // 12.58 MB
  unsigned short* kbb  = (unsigned short*)(ws + 81788928);       // 12.58 MB
  // flash partials overlay the dead qkvb region (WAR-safe, stream-ordered):
  unsigned short* pO   = (unsigned short*)(ws + 31457280);       // 25.17 MB bf16 [768][128][128]
  float*          pls  = (float*)(ws + 31457280 + 25165824);     // 0.39 MB
  float*          pm   = (float*)(ws + 31457280 + 25165824 + 393216); // 0.39 MB
  unsigned short* vt   = (unsigned short*)d_out;                 // scratch; overwritten later
  unsigned short* obb  = xb;                                     // attn-out aliases xb
  float* out = (float*)d_out;

  prep<<<3328, 256, 0, stream>>>(x, xb, Wq, Wk, Wv, Wo, Wt);
  gemm256b<<<dim3(18, 16), 512, 0, stream>>>(xb, Wt, qkvb, bq, bk, bv, NTOK, 3 * DIM, DIM, 0, 1);
  rmsv<<<4864, 256, 0, stream>>>(qkvb, gq, gk, grids, fcos, fsin, qbb, kbb, vt);
  flash<<<dim3(16, 12, 4), 256, 0, stream>>>(qbb, kbb, vt, seq, pO, pls, pm);
  merge<<<dim3(16, 12, 2), 256, 0, stream>>>(pO, pls, pm, obb);
  gemm_bt<<<dim3(12, 32), 256, 0, stream>>>(obb, Wt + (size_t)3 * DIM * DIM, out,
                                            bo, bo, bo, NTOK, DIM, DIM, 1, 0);
}

// Round 17
// 242.150 us; speedup vs baseline: 3.9016x; 3.9016x over previous
//
#include <hip/hip_runtime.h>
#include <hip/hip_bf16.h>

#define DIM   1536
#define HEADS 12
#define HD    128
#define LSEQ  2048
#define NB    2
#define NTOK  (NB*LSEQ)   // 4096

using f32x4  = __attribute__((ext_vector_type(4))) float;
using f32x16 = __attribute__((ext_vector_type(16))) float;
using s16x8  = __attribute__((ext_vector_type(8))) short;
using u16x4  = __attribute__((ext_vector_type(4))) unsigned short;

__device__ __forceinline__ unsigned short f2bf(float f) {
  unsigned int u = __builtin_bit_cast(unsigned int, f);
  u += 0x7fffu + ((u >> 16) & 1u);   // RNE
  return (unsigned short)(u >> 16);
}
__device__ __forceinline__ float bf2f(unsigned short u) {
  return __builtin_bit_cast(float, (unsigned int)u << 16);
}
// HW packed f32x2 -> bf16x2 (lo=a, hi=b), RNE
__device__ __forceinline__ unsigned pk2(float a, float b) {
  unsigned r;
  asm("v_cvt_pk_bf16_f32 %0, %1, %2" : "=v"(r) : "v"(a), "v"(b));
  return r;
}
__device__ __forceinline__ unsigned long long pack4bf(float a, float b, float c, float d) {
  return (unsigned long long)f2bf(a) | ((unsigned long long)f2bf(b) << 16) |
         ((unsigned long long)f2bf(c) << 32) | ((unsigned long long)f2bf(d) << 48);
}
// swaps x.lanes[32:63] <-> y.lanes[0:31]
__device__ __forceinline__ void plswap(unsigned &x, unsigned &y) {
  asm volatile("v_permlane32_swap_b32 %0, %1" : "+v"(x), "+v"(y));
}
__device__ __forceinline__ void gload_lds16(const void* g, void* l) {
  __builtin_amdgcn_global_load_lds(
      (__attribute__((address_space(1))) void*)const_cast<void*>(g),
      (__attribute__((address_space(3))) void*)l,
      16, 0, 0);
}

// ---- prep: wtrans (blocks 0..2303) || cvt_x (blocks 2304..3327) ----
__global__ __launch_bounds__(256) void prep(
    const float* __restrict__ x, unsigned short* __restrict__ xb,
    const float* __restrict__ W0, const float* __restrict__ W1,
    const float* __restrict__ W2, const float* __restrict__ W3,
    unsigned short* __restrict__ Wt) {
  __shared__ unsigned short t[64][68];
  const int bid = blockIdx.x;
  const int tid = threadIdx.x;
  if (bid < 2304) {
    const int z = bid / 576, rem = bid % 576;
    const float* W = z == 0 ? W0 : z == 1 ? W1 : z == 2 ? W2 : W3;
    unsigned short* out = Wt + (size_t)z * DIM * DIM;
    const int n0 = (rem % 24) * 64, k0 = (rem / 24) * 64;
#pragma unroll
    for (int i = 0; i < 16; i++) {
      int idx = tid + i * 256;
      int r = idx >> 6, c = idx & 63;
      t[r][c] = f2bf(W[(size_t)(k0 + r) * DIM + n0 + c]);
    }
    __syncthreads();
#pragma unroll
    for (int i = 0; i < 16; i++) {
      int idx = tid + i * 256;
      int r = idx >> 6, c = idx & 63;
      out[(size_t)(n0 + r) * DIM + k0 + c] = t[c][r];
    }
  } else {
    int i = ((bid - 2304) * 256 + tid) * 4;
    int stride = 1024 * 256 * 4;
    for (; i < NTOK * DIM; i += stride) {
      f32x4 v = *(const f32x4*)(x + i);
      u16x4 o;
      o[0] = f2bf(v[0]); o[1] = f2bf(v[1]); o[2] = f2bf(v[2]); o[3] = f2bf(v[3]);
      *(u16x4*)(xb + i) = o;
    }
  }
}

// ---------------- GEMM: C[M][N] = A @ Bt^T + bias; f32 or bf16 out ----------------
// 128x128 tile, BK=64, 4 waves — verified m97-structure (~3-4 blocks/CU, no tail).
__global__ __launch_bounds__(256) void gemm_bt(
    const unsigned short* __restrict__ A, const unsigned short* __restrict__ Bt,
    void* __restrict__ Cv,
    const float* __restrict__ b0, const float* __restrict__ b1, const float* __restrict__ b2,
    int M, int N, int K, int biasMode, int outBf16) {
  __shared__ __align__(16) unsigned short As[128 * 64];
  __shared__ __align__(16) unsigned short Bs[128 * 64];
  const int tid = threadIdx.x;
  const int lane = tid & 63, w = tid >> 6;
  const int wr = w >> 1, wc = w & 1;
  const int l15 = lane & 15, g4 = lane >> 4;
  // XCD-aware bijective swizzle (nwg % 8 == 0 for both launch configs)
  const int nwg = gridDim.x * gridDim.y;
  const int bidf = blockIdx.y * gridDim.x + blockIdx.x;
  const int cpx = nwg >> 3;
  const int sw = (bidf & 7) * cpx + (bidf >> 3);
  const int m0 = (sw / gridDim.x) * 128, n0 = (sw % gridDim.x) * 128;

  f32x4 acc[4][4];
#pragma unroll
  for (int i = 0; i < 4; i++)
#pragma unroll
    for (int j = 0; j < 4; j++) acc[i][j] = (f32x4){0.f, 0.f, 0.f, 0.f};

  for (int kt = 0; kt < K; kt += 64) {
    __syncthreads();
#pragma unroll
    for (int i = 0; i < 4; i++) {
      int c = tid + i * 256;
      int row = c >> 3, g = c & 7;
      int gs = g ^ (row & 7);
      gload_lds16(A + (size_t)(m0 + row) * K + kt + gs * 8, As + c * 8);
    }
#pragma unroll
    for (int i = 0; i < 4; i++) {
      int c = tid + i * 256;
      int row = c >> 3, g = c & 7;
      int gs = g ^ (row & 7);
      gload_lds16(Bt + (size_t)(n0 + row) * K + kt + gs * 8, Bs + c * 8);
    }
    __syncthreads();
#pragma unroll
    for (int kk = 0; kk < 2; kk++) {
      s16x8 af[4], bfr[4];
#pragma unroll
      for (int m = 0; m < 4; m++) {
        int row = wr * 64 + m * 16 + l15;
        int off = row * 128 + ((kk * 64 + g4 * 16) ^ ((row & 7) << 4));
        af[m] = *(const s16x8*)((const char*)As + off);
      }
#pragma unroll
      for (int n = 0; n < 4; n++) {
        int row = wc * 64 + n * 16 + l15;
        int off = row * 128 + ((kk * 64 + g4 * 16) ^ ((row & 7) << 4));
        bfr[n] = *(const s16x8*)((const char*)Bs + off);
      }
#pragma unroll
      for (int m = 0; m < 4; m++)
#pragma unroll
        for (int n = 0; n < 4; n++)
          acc[m][n] = __builtin_amdgcn_mfma_f32_16x16x32_bf16(af[m], bfr[n], acc[m][n], 0, 0, 0);
    }
  }
#pragma unroll
  for (int m = 0; m < 4; m++)
#pragma unroll
    for (int n = 0; n < 4; n++)
#pragma unroll
      for (int r = 0; r < 4; r++) {
        int grow = m0 + wr * 64 + m * 16 + g4 * 4 + r;
        int gcol = n0 + wc * 64 + n * 16 + l15;
        float bias = (biasMode == 1)
                         ? b0[gcol]
                         : (gcol < 1536 ? b0[gcol]
                                        : (gcol < 3072 ? b1[gcol - 1536] : b2[gcol - 3072]));
        float val = acc[m][n][r] + bias;
        if (outBf16) ((unsigned short*)Cv)[(size_t)grow * N + gcol] = f2bf(val);
        else         ((float*)Cv)[(size_t)grow * N + gcol] = val;
      }
}

// ---- rmsv: rmsrope (blocks 0..4095) || vtrans (blocks 4096..4863) ----
__global__ __launch_bounds__(256) void rmsv(
    const unsigned short* __restrict__ qkvb,   // [4096][4608] bf16
    const float* __restrict__ gq, const float* __restrict__ gk,
    const int* __restrict__ grid_sizes,
    const float* __restrict__ fcos, const float* __restrict__ fsin,
    unsigned short* __restrict__ qb, unsigned short* __restrict__ kb,
    unsigned short* __restrict__ vt) {
  __shared__ float qrow[1536], krow[1536];
  __shared__ float red[8];
  __shared__ unsigned short tile[64][130];
  const int tid = threadIdx.x;
  if (blockIdx.x < 4096) {
    const int t = blockIdx.x;
    const int b = t >> 11, l = t & 2047;
    const unsigned short* rq = qkvb + (size_t)t * 4608;
    const unsigned short* rk = rq + 1536;
    float sq = 0.f, sk = 0.f;
    if (tid < 192) {
      s16x8 vq = *(const s16x8*)(rq + tid * 8);
      s16x8 vk = *(const s16x8*)(rk + tid * 8);
#pragma unroll
      for (int j = 0; j < 8; j++) {
        float a = bf2f((unsigned short)vq[j]); qrow[tid * 8 + j] = a; sq += a * a;
        float c = bf2f((unsigned short)vk[j]); krow[tid * 8 + j] = c; sk += c * c;
      }
    }
    for (int o = 32; o; o >>= 1) { sq += __shfl_down(sq, o); sk += __shfl_down(sk, o); }
    if ((tid & 63) == 0) { red[tid >> 6] = sq; red[4 + (tid >> 6)] = sk; }
    __syncthreads();
    const float rsq = rsqrtf((red[0] + red[1] + red[2] + red[3]) * (1.f / 1536.f) + 1e-6f);
    const float rsk = rsqrtf((red[4] + red[5] + red[6] + red[7]) * (1.f / 1536.f) + 1e-6f);
    const float QS = 0.08838834764831845f * 1.4426950408889634f;  // 1/sqrt(128)*log2e
    const int fg = grid_sizes[b * 3 + 0], hg = grid_sizes[b * 3 + 1], wg = grid_sizes[b * 3 + 2];
    const int hw = hg * wg;
    const bool valid = l < fg * hw;
    const int fi = valid ? l / hw : 0;
    const int hi = valid ? (l / wg) % hg : 0;
    const int wi = valid ? l % wg : 0;
    const size_t obase = (((size_t)b * HEADS) * LSEQ + l) * HD;
    for (int i = tid; i < HEADS * 64; i += 256) {
      int hd = i >> 6, j = i & 63;
      float c, s;
      if (valid) {
        int idx = j < 22 ? fi : (j < 43 ? hi : wi);
        c = fcos[idx * 64 + j]; s = fsin[idx * 64 + j];
      } else { c = 1.f; s = 0.f; }
      int col = hd * 128 + 2 * j;
      size_t o = obase + (size_t)hd * LSEQ * HD + 2 * j;
      float xr = qrow[col] * rsq * gq[col];
      float xi = qrow[col + 1] * rsq * gq[col + 1];
      float q0 = (xr * c - xi * s) * QS, q1 = (xr * s + xi * c) * QS;
      *(unsigned int*)(qb + o) = (unsigned int)f2bf(q0) | ((unsigned int)f2bf(q1) << 16);
      xr = krow[col] * rsk * gk[col];
      xi = krow[col + 1] * rsk * gk[col + 1];
      *(unsigned int*)(kb + o) =
          (unsigned int)f2bf(xr * c - xi * s) | ((unsigned int)f2bf(xr * s + xi * c) << 16);
    }
  } else {
    const int r = blockIdx.x - 4096;            // 0..767
    const int lt = r & 31, hb = r >> 5;
    const int h = hb % 12, b = hb / 12;
    const int l0 = lt * 64;
#pragma unroll
    for (int i = 0; i < 4; i++) {
      int idx = tid + i * 256;
      int tk = idx >> 4, dc = (idx & 15) * 8;
      s16x8 v = *(const s16x8*)(qkvb + (size_t)(b * 2048 + l0 + tk) * 4608 + 3072 + h * 128 + dc);
#pragma unroll
      for (int j = 0; j < 8; j++) tile[tk][dc + j] = (unsigned short)v[j];
    }
    __syncthreads();
    const size_t ob = (((size_t)b * HEADS + h) * HD) * LSEQ + l0;
#pragma unroll
    for (int i = 0; i < 4; i++) {
      int idx = tid + i * 256;
      int d = idx >> 3, ck = (idx & 7) * 8;
      s16x8 o;
#pragma unroll
      for (int j = 0; j < 8; j++) o[j] = (short)tile[ck + j][d];
      *(s16x8*)(vt + ob + (size_t)d * LSEQ + ck) = o;
    }
  }
}

// ---- flash partial: 32x32 swapped, 4-wave blocks (128 q), KVBLK=32, split-2 KV ----
__global__ __launch_bounds__(256) void flash(
    const unsigned short* __restrict__ qb, const unsigned short* __restrict__ kb,
    const unsigned short* __restrict__ vt, const int* __restrict__ seq_lens,
    unsigned short* __restrict__ pO, float* __restrict__ pls, float* __restrict__ pm) {
  // 768 blocks; XCD swizzle: 96 consecutive wg per XCD
  const int orig = blockIdx.x + 16 * (blockIdx.y + 12 * blockIdx.z);
  const int wg = (orig & 7) * 96 + (orig >> 3);
  const int qt = wg & 15;
  const int r4 = wg >> 4;              // 0..47
  const int hh = r4 % 12;
  const int z2 = r4 / 12;              // 0..3
  const int b = z2 >> 1, half = z2 & 1;
  const int tid = threadIdx.x, lane = tid & 63, w = tid >> 6;   // w in {0..3}
  const int l31 = lane & 31, hi = lane >> 5;
  __shared__ __align__(16) unsigned short Ks[2][32 * 128];  // [key][d] 8KB each
  __shared__ __align__(16) unsigned short Vs[2][128 * 32];  // [d][key] 8KB each
  const size_t bh = (size_t)b * HEADS + hh;
  const int q0 = qt * 128 + w * 32;

  s16x8 qf[8];
  {
    const unsigned short* qp = qb + (bh * LSEQ + q0 + l31) * HD + hi * 8;
#pragma unroll
    for (int s = 0; s < 8; s++) qf[s] = *(const s16x8*)(qp + s * 16);
  }
  const int ntile = seq_lens[b] >> 5;        // 64 or 48 (even)
  const int htiles = ntile >> 1;             // 32 or 24 (even)
  const int k0t = half * htiles;             // even
  const int kend = k0t + htiles;
  asm volatile("s_waitcnt vmcnt(0)" ::: "memory");  // drain Q; exact counts below

  f32x16 acc[4];
#pragma unroll
  for (int d = 0; d < 4; d++)
#pragma unroll
    for (int r = 0; r < 16; r++) acc[d][r] = 0.f;
  float mrow = -1e30f, ls = 0.f;

#define STAGE_K(T, BUF)                                                                \
  _Pragma("unroll") for (int i = 0; i < 2; i++) {                                      \
    int c = tid + i * 256, row = c >> 4, seg = c & 15, ss = seg ^ (row & 15);          \
    gload_lds16(kb + (bh * LSEQ + (T) * 32 + row) * HD + ss * 8, &Ks[BUF][0] + c * 8); \
  }
#define STAGE_V(T, BUF)                                                                \
  _Pragma("unroll") for (int i = 0; i < 2; i++) {                                      \
    int c = tid + i * 256, row = c >> 2, seg = c & 3, ss = seg ^ ((row >> 1) & 3);     \
    gload_lds16(vt + (bh * HD + row) * LSEQ + (T) * 32 + ss * 8, &Vs[BUF][0] + c * 8); \
  }

  STAGE_K(k0t, 0); STAGE_V(k0t, 0);
  STAGE_K(k0t + 1, 1); STAGE_V(k0t + 1, 1);

  for (int kt = k0t; kt < kend; kt++) {
    const int cur = kt & 1;
    asm volatile("s_waitcnt vmcnt(4)" ::: "memory");
    __builtin_amdgcn_s_barrier();
    __builtin_amdgcn_sched_barrier(0);
    f32x16 st0;
#pragma unroll
    for (int r = 0; r < 16; r++) st0[r] = 0.f;
    const char* ksb = (const char*)&Ks[cur][0];
    __builtin_amdgcn_s_setprio(1);
#pragma unroll
    for (int s = 0; s < 8; s++) {
      int g = 2 * s + hi;
      s16x8 kf = *(const s16x8*)(ksb + l31 * 256 + ((g ^ (l31 & 15)) << 4));
      st0 = __builtin_amdgcn_mfma_f32_32x32x16_bf16(kf, qf[s], st0, 0, 0, 0);
    }
    __builtin_amdgcn_s_setprio(0);
    f32x16 mt;
#pragma unroll
    for (int r = 0; r < 16; r++) mt[r] = st0[r];
#pragma unroll
    for (int off = 8; off; off >>= 1)
#pragma unroll
      for (int r = 0; r < off; r++) mt[r] = fmaxf(mt[r], mt[r + off]);
    float mx = fmaxf(mt[0], __shfl_xor(mt[0], 32));
    const bool grow = mx > mrow + 8.0f;
    const float alpha = grow ? exp2f(mrow - mx) : 1.f;
    if (grow) mrow = mx;
#pragma unroll
    for (int r = 0; r < 16; r++) st0[r] = exp2f(st0[r] - mrow);
    f32x16 sm;
#pragma unroll
    for (int r = 0; r < 16; r++) sm[r] = st0[r];
#pragma unroll
    for (int off = 8; off; off >>= 1)
#pragma unroll
      for (int r = 0; r < off; r++) sm[r] += sm[r + off];
    ls = ls * alpha + (sm[0] + __shfl_xor(sm[0], 32));
    if (__any((int)grow)) {
#pragma unroll
      for (int d = 0; d < 4; d++)
#pragma unroll
        for (int r = 0; r < 16; r++) acc[d][r] *= alpha;
    }
    union U { unsigned u[4]; s16x8 v; } pa0, pa1;
    {
      unsigned c0 = pk2(st0[0], st0[1]),  c1 = pk2(st0[2], st0[3]);
      unsigned c2 = pk2(st0[4], st0[5]),  c3 = pk2(st0[6], st0[7]);
      unsigned c4 = pk2(st0[8], st0[9]),  c5 = pk2(st0[10], st0[11]);
      unsigned c6 = pk2(st0[12], st0[13]), c7 = pk2(st0[14], st0[15]);
      plswap(c0, c2); plswap(c1, c3); plswap(c4, c6); plswap(c5, c7);
      pa0.u[0] = c0; pa0.u[1] = c1; pa0.u[2] = c2; pa0.u[3] = c3;
      pa1.u[0] = c4; pa1.u[1] = c5; pa1.u[2] = c6; pa1.u[3] = c7;
    }
    const char* vsb = (const char*)&Vs[cur][0];
    __builtin_amdgcn_s_setprio(1);
#pragma unroll
    for (int slot = 0; slot < 2; slot++) {
      s16x8 pb = slot == 0 ? pa0.v : pa1.v;
      int g = 2 * slot + hi;
#pragma unroll
      for (int d = 0; d < 4; d++) {
        int row = d * 32 + l31;
        s16x8 vf = *(const s16x8*)(vsb + row * 64 + ((g ^ ((row >> 1) & 3)) << 4));
        acc[d] = __builtin_amdgcn_mfma_f32_32x32x16_bf16(vf, pb, acc[d], 0, 0, 0);
      }
    }
    __builtin_amdgcn_s_setprio(0);
    __builtin_amdgcn_s_barrier();
    __builtin_amdgcn_sched_barrier(0);
    {
      int knext = (kt + 2 < kend) ? kt + 2 : kt;
      STAGE_K(knext, cur); STAGE_V(knext, cur);
    }
  }
  asm volatile("s_waitcnt vmcnt(0)" ::: "memory");
#undef STAGE_K
#undef STAGE_V
  const int p = ((b * 12 + hh) * 16 + qt) * 2 + half;
  const int ql = w * 32 + l31;                 // 0..127
  unsigned short* pop = pO + ((size_t)p * 128 + ql) * 128 + hi * 4;
#pragma unroll
  for (int d = 0; d < 4; d++)
#pragma unroll
    for (int j = 0; j < 4; j++) {
      unsigned long long pk = pack4bf(acc[d][4 * j], acc[d][4 * j + 1],
                                      acc[d][4 * j + 2], acc[d][4 * j + 3]);
      *(unsigned long long*)(pop + d * 32 + 8 * j) = pk;
    }
  if (hi == 0) {
    pls[(size_t)p * 128 + ql] = ls;
    pm[(size_t)p * 128 + ql] = mrow;
  }
}

// ---- merge two KV-half partials -> attn out [token][h*128+d] bf16 ----
__global__ __launch_bounds__(256) void merge(
    const unsigned short* __restrict__ pO, const float* __restrict__ pls,
    const float* __restrict__ pm, unsigned short* __restrict__ ob) {
  const int qt = blockIdx.x, h = blockIdx.y, b = blockIdx.z;
  const int p0 = ((b * 12 + h) * 16 + qt) * 2;
  const int tid = threadIdx.x;
#pragma unroll
  for (int i = tid; i < 2048; i += 256) {
    int q = i >> 4, c = (i & 15) * 8;
    float m0 = pm[(size_t)p0 * 128 + q],  m1 = pm[(size_t)(p0 + 1) * 128 + q];
    float l0 = pls[(size_t)p0 * 128 + q], l1 = pls[(size_t)(p0 + 1) * 128 + q];
    float m = fmaxf(m0, m1);
    float a0 = exp2f(m0 - m), a1 = exp2f(m1 - m);
    float inv = 1.f / (a0 * l0 + a1 * l1);
    a0 *= inv; a1 *= inv;
    s16x8 o0 = *(const s16x8*)(pO + ((size_t)p0 * 128 + q) * 128 + c);
    s16x8 o1 = *(const s16x8*)(pO + ((size_t)(p0 + 1) * 128 + q) * 128 + c);
    s16x8 o;
#pragma unroll
    for (int j = 0; j < 8; j++)
      o[j] = (short)f2bf(bf2f((unsigned short)o0[j]) * a0 + bf2f((unsigned short)o1[j]) * a1);
    *(s16x8*)(ob + ((size_t)(b * LSEQ) + qt * 128 + q) * DIM + h * HD + c) = o;
  }
}

// ---------------- launch ----------------
extern "C" void kernel_launch(void* const* d_in, const int* in_sizes, int n_in,
                              void* d_out, int out_size, void* d_ws, size_t ws_size,
                              hipStream_t stream) {
  const float* x    = (const float*)d_in[0];
  const int*   seq  = (const int*)d_in[1];
  const int*   grids= (const int*)d_in[2];
  const float* fcos = (const float*)d_in[3];
  const float* fsin = (const float*)d_in[4];
  const float* Wq   = (const float*)d_in[5];
  const float* bq   = (const float*)d_in[6];
  const float* Wk   = (const float*)d_in[7];
  const float* bk   = (const float*)d_in[8];
  const float* Wv   = (const float*)d_in[9];
  const float* bv   = (const float*)d_in[10];
  const float* Wo   = (const float*)d_in[11];
  const float* bo   = (const float*)d_in[12];
  const float* gq   = (const float*)d_in[13];
  const float* gk   = (const float*)d_in[14];

  char* ws = (char*)d_ws;
  unsigned short* xb   = (unsigned short*)(ws);                  // 12.58 MB (reused: attn-out)
  unsigned short* Wt   = (unsigned short*)(ws + 12582912);       // 18.87 MB
  unsigned short* qkvb = (unsigned short*)(ws + 31457280);       // 37.75 MB (dead after rmsv)
  unsigned short* qbb  = (unsigned short*)(ws + 69206016);       // 12.58 MB
  unsigned short* kbb  = (unsigned short*)(ws + 81788928);       // 12.58 MB
  // flash partials overlay the dead qkvb region (WAR-safe, stream-ordered):
  unsigned short* pO   = (unsigned short*)(ws + 31457280);       // 25.17 MB bf16 [768][128][128]
  float*          pls  = (float*)(ws + 31457280 + 25165824);     // 0.39 MB
  float*          pm   = (float*)(ws + 31457280 + 25165824 + 393216); // 0.39 MB
  unsigned short* vt   = (unsigned short*)d_out;                 // scratch; overwritten later
  unsigned short* obb  = xb;                                     // attn-out aliases xb
  float* out = (float*)d_out;

  prep<<<3328, 256, 0, stream>>>(x, xb, Wq, Wk, Wv, Wo, Wt);
  gemm_bt<<<dim3(36, 32), 256, 0, stream>>>(xb, Wt, qkvb, bq, bk, bv, NTOK, 3 * DIM, DIM, 0, 1);
  rmsv<<<4864, 256, 0, stream>>>(qkvb, gq, gk, grids, fcos, fsin, qbb, kbb, vt);
  flash<<<dim3(16, 12, 4), 256, 0, stream>>>(qbb, kbb, vt, seq, pO, pls, pm);
  merge<<<dim3(16, 12, 2), 256, 0, stream>>>(pO, pls, pm, obb);
  gemm_bt<<<dim3(12, 32), 256, 0, stream>>>(obb, Wt + (size_t)3 * DIM * DIM, out,
                                            bo, bo, bo, NTOK, DIM, DIM, 1, 0);
}